// Round 4
// baseline (2704.855 us; speedup 1.0000x reference)
//
#include <hip/hip_runtime.h>
#include <hip/hip_bf16.h>

// Problem constants
#define B_ 256
#define T_ 96
#define F_ 368
#define H_ 368
#define G3_ 1104          // 3*H
#define NC_ 29            // fine classes
#define BT_ (B_*T_)       // 24576
#define HB_ (H_*B_)       // 94208, one time-slice of temporal [u][b]

// GRU geometry
#define NSL 8             // unit slices
#define NU 46             // units per slice (8*46 = 368)
#define NCOL 138          // cols per slice = 3*NU
#define SLSTRIDE 144      // padded col positions per slice (64+64+16)
#define WQCOLS 1152       // 8 * 144
#define ROWS 8            // batch rows per group

#define F4C(v, i) ((i)==0?(v).x:((i)==1?(v).y:((i)==2?(v).z:(v).w)))

// ---------------------------------------------------------------------------
// K0: pack Wh (1104x368) into Wq float4 blocks [kb=92][1152 colpos]
// ---------------------------------------------------------------------------
__global__ __launch_bounds__(256) void k_prep_wq(const float* __restrict__ Wh,
                                                 float4* __restrict__ Wq) {
    const int idx = blockIdx.x*256 + threadIdx.x;   // < 92*1152 = 105984
    const int kb = idx / WQCOLS, cp = idx - kb*WQCOLS;
    const int us = cp / SLSTRIDE, r = cp - us*SLSTRIDE;
    float4 v = make_float4(0.f,0.f,0.f,0.f);
    if (r < NCOL) {
        const int g = r / NU, u = r - g*NU;
        const int grow = g*H_ + us*NU + u;          // < 1104
        v = *reinterpret_cast<const float4*>(Wh + (size_t)grow*H_ + 4*kb);
    }
    Wq[idx] = v;
}

// ---------------------------------------------------------------------------
// K0b: pack head weights Wcat[u][32]
// ---------------------------------------------------------------------------
__global__ __launch_bounds__(256) void k_prep_wcat(const float* __restrict__ Wc,
                                                   const float* __restrict__ Wf,
                                                   float* __restrict__ Wcat) {
    const int idx = blockIdx.x*256 + threadIdx.x;   // < 368*32 = 11776
    const int u = idx >> 5, c = idx & 31;
    float v = 0.f;
    if (c < 2) v = Wc[c*H_ + u];
    else if (c < 31) v = Wf[(c-2)*H_ + u];
    Wcat[idx] = v;
}

// ---------------------------------------------------------------------------
// K0c: zero the barrier counters (ws is re-poisoned 0xAA before every call)
// ---------------------------------------------------------------------------
__global__ __launch_bounds__(256) void k_zero_bar(int* __restrict__ bar) {
    bar[blockIdx.x*256 + threadIdx.x] = 0;          // 8 blocks -> 2048 ints
}

// ---------------------------------------------------------------------------
// K1 v3: xproj GEMM, 128x128 tile, software-pipelined global loads.
// ---------------------------------------------------------------------------
__global__ __launch_bounds__(256) void k_xproj_gemm(const float* __restrict__ A,
                                                    const float* __restrict__ Bw,
                                                    const float* __restrict__ bias,
                                                    float* __restrict__ C) {
    __shared__ float As[16][128];
    __shared__ float Bs[16][128];
    const int tid = threadIdx.x;
    const int tx = tid & 15, ty = tid >> 4;
    const int gm0 = blockIdx.y * 128, gn0 = blockIdx.x * 128;
    const float4* A4 = reinterpret_cast<const float4*>(A);   // row stride 92
    const float4* B4 = reinterpret_cast<const float4*>(Bw);
    const int lm = tid & 127;
    const int kh = (tid >> 7) * 2;
    const int gn = gn0 + lm;

    float acc[8][8];
    #pragma unroll
    for (int i = 0; i < 8; ++i)
        #pragma unroll
        for (int j = 0; j < 8; ++j) acc[i][j] = 0.f;

    float4 va[2], vb[2];
    #pragma unroll
    for (int q = 0; q < 2; ++q) {
        va[q] = A4[(size_t)(gm0 + lm)*92 + kh + q];
        vb[q] = (gn < G3_) ? B4[(size_t)gn*92 + kh + q] : make_float4(0.f,0.f,0.f,0.f);
    }

    for (int kt = 0; kt < 23; ++kt) {
        __syncthreads();   // previous iteration's LDS reads done
        #pragma unroll
        for (int q = 0; q < 2; ++q) {
            As[(kh+q)*4+0][lm] = va[q].x; As[(kh+q)*4+1][lm] = va[q].y;
            As[(kh+q)*4+2][lm] = va[q].z; As[(kh+q)*4+3][lm] = va[q].w;
            Bs[(kh+q)*4+0][lm] = vb[q].x; Bs[(kh+q)*4+1][lm] = vb[q].y;
            Bs[(kh+q)*4+2][lm] = vb[q].z; Bs[(kh+q)*4+3][lm] = vb[q].w;
        }
        __syncthreads();
        // prefetch next k-tile (clamped; redundant at kt==22, discarded)
        const int ktn = (kt < 22) ? kt + 1 : 22;
        #pragma unroll
        for (int q = 0; q < 2; ++q) {
            va[q] = A4[(size_t)(gm0 + lm)*92 + ktn*4 + kh + q];
            vb[q] = (gn < G3_) ? B4[(size_t)gn*92 + ktn*4 + kh + q]
                               : make_float4(0.f,0.f,0.f,0.f);
        }
        #pragma unroll
        for (int k = 0; k < 16; ++k) {
            const float4 a0 = *reinterpret_cast<const float4*>(&As[k][ty*4]);
            const float4 a1 = *reinterpret_cast<const float4*>(&As[k][64 + ty*4]);
            const float4 b0 = *reinterpret_cast<const float4*>(&Bs[k][tx*4]);
            const float4 b1 = *reinterpret_cast<const float4*>(&Bs[k][64 + tx*4]);
            #pragma unroll
            for (int i = 0; i < 4; ++i) {
                const float ai0 = F4C(a0, i), ai1 = F4C(a1, i);
                #pragma unroll
                for (int j = 0; j < 4; ++j) {
                    const float bj0 = F4C(b0, j), bj1 = F4C(b1, j);
                    acc[i][j]     = fmaf(ai0, bj0, acc[i][j]);
                    acc[i][j+4]   = fmaf(ai0, bj1, acc[i][j+4]);
                    acc[i+4][j]   = fmaf(ai1, bj0, acc[i+4][j]);
                    acc[i+4][j+4] = fmaf(ai1, bj1, acc[i+4][j+4]);
                }
            }
        }
    }
    #pragma unroll
    for (int i = 0; i < 8; ++i) {
        const int gm = gm0 + ((i < 4) ? (ty*4 + i) : (64 + ty*4 + i - 4));
        #pragma unroll
        for (int j = 0; j < 8; ++j) {
            const int gnn = gn0 + ((j < 4) ? (tx*4 + j) : (64 + tx*4 + j - 4));
            if (gnn < G3_) C[(size_t)gm*G3_ + gnn] = acc[i][j] + bias[gnn];
        }
    }
}

// ---------------------------------------------------------------------------
// K2 v3: PERSISTENT GRU — all 96 steps in one kernel. 256 WGs = 32 bg x 8 us.
// Cross-WG h exchange only among the 8 WGs sharing bg (same XCD under %8
// swizzle). Sync via per-bg monotonic arrival counter (device-scope atomics,
// correct regardless of XCD mapping).
// ---------------------------------------------------------------------------
__global__ __launch_bounds__(256) void k_gru_all(const float* __restrict__ xproj,
                                                 const float4* __restrict__ Wq,
                                                 const float* __restrict__ bh,
                                                 float* __restrict__ temporal,
                                                 int* __restrict__ bar) {
    __shared__ float part[4][ROWS][SLSTRIDE];   // 18,432 B
    __shared__ float hsl[H_*ROWS];              // 11,776 B
    const int tid = threadIdx.x;
    const int xcd = blockIdx.x & 7;
    const int j   = blockIdx.x >> 3;
    const int bg  = 4*xcd + (j >> 3);           // 0..31 (all 8 us-WGs: same XCD)
    const int us  = j & 7;
    const int b0  = bg * ROWS;
    const int wq  = tid >> 6;
    const int l   = tid & 63;
    const int l3  = 128 + (l & 15);
    int* mybar = bar + bg*64;                   // 256 B spacing per counter

    // constant gate-phase indices
    const int u1 = tid % NU, r1 = tid / NU;     // item1 = tid (<368 always)
    const int ug1 = us*NU + u1;
    const int i2 = tid + 256;
    const int u2 = i2 % NU, r2 = i2 / NU;       // item2 valid iff tid < 112
    const int ug2 = us*NU + u2;
    const bool has2 = (i2 < ROWS*NU);

    const float bh1r = bh[ug1], bh1z = bh[H_+ug1], bh1n = bh[2*H_+ug1];
    float bh2r = 0.f, bh2z = 0.f, bh2n = 0.f;
    if (has2) { bh2r = bh[ug2]; bh2z = bh[H_+ug2]; bh2n = bh[2*H_+ug2]; }

    const float4* wp  = Wq + (size_t)(wq*23)*WQCOLS + us*SLSTRIDE;
    const float4* hs4 = reinterpret_cast<const float4*>(hsl) + (size_t)wq*184;

    for (int t = 0; t < T_; ++t) {
        float* hout = temporal + (size_t)t*HB_;

        // prefetch gate operands (independent of h -> hides under spin)
        const float* xr1 = xproj + ((size_t)(b0 + r1)*T_ + t)*G3_;
        const float xg10 = xr1[ug1], xg11 = xr1[H_+ug1], xg12 = xr1[2*H_+ug1];
        float xg20 = 0.f, xg21 = 0.f, xg22 = 0.f;
        if (has2) {
            const float* xr2 = xproj + ((size_t)(b0 + r2)*T_ + t)*G3_;
            xg20 = xr2[ug2]; xg21 = xr2[H_+ug2]; xg22 = xr2[2*H_+ug2];
        }

        float acc[ROWS][3];
        #pragma unroll
        for (int r = 0; r < ROWS; ++r) { acc[r][0]=0.f; acc[r][1]=0.f; acc[r][2]=0.f; }

        if (t > 0) {
            // wait for all 8 bg-siblings to have published h(t-1)
            if (tid == 0) {
                while (__hip_atomic_load(mybar, __ATOMIC_ACQUIRE,
                                         __HIP_MEMORY_SCOPE_AGENT) < 8*t) {}
            }
            __syncthreads();
            const float* hin = temporal + (size_t)(t - 1)*HB_;
            // stage h(t-1)[all k][b0..b0+7] into LDS
            #pragma unroll
            for (int ii = 0; ii < 12; ++ii) {
                const int i = tid + ii*256;
                if (i < H_*ROWS) hsl[i] = hin[(size_t)(i >> 3)*B_ + b0 + (i & 7)];
            }
            __syncthreads();
            // inner product: 23 kk, W software-pipelined from L2
            float4 w0 = wp[l], w1 = wp[64 + l], w2 = wp[l3];
            for (int kk = 0; kk < 23; ++kk) {
                const int kkn = (kk < 22) ? kk + 1 : 22;
                const float4* np = wp + (size_t)kkn*WQCOLS;
                const float4 nw0 = np[l], nw1 = np[64 + l], nw2 = np[l3];
                #pragma unroll
                for (int jk = 0; jk < 4; ++jk) {
                    const float4 h0 = hs4[kk*8 + jk*2];
                    const float4 h1 = hs4[kk*8 + jk*2 + 1];
                    const float wa = F4C(w0, jk), wb = F4C(w1, jk), wc = F4C(w2, jk);
                    #pragma unroll
                    for (int r = 0; r < 4; ++r) {
                        const float hv = F4C(h0, r);
                        acc[r][0] = fmaf(hv, wa, acc[r][0]);
                        acc[r][1] = fmaf(hv, wb, acc[r][1]);
                        acc[r][2] = fmaf(hv, wc, acc[r][2]);
                    }
                    #pragma unroll
                    for (int r = 0; r < 4; ++r) {
                        const float hv = F4C(h1, r);
                        acc[4+r][0] = fmaf(hv, wa, acc[4+r][0]);
                        acc[4+r][1] = fmaf(hv, wb, acc[4+r][1]);
                        acc[4+r][2] = fmaf(hv, wc, acc[4+r][2]);
                    }
                }
                w0 = nw0; w1 = nw1; w2 = nw2;
            }
        } else {
            __syncthreads();   // keep barrier structure uniform at t=0
        }

        // k-quarter partials
        #pragma unroll
        for (int r = 0; r < ROWS; ++r) {
            part[wq][r][l]      = acc[r][0];
            part[wq][r][64 + l] = acc[r][1];
            part[wq][r][l3]     = acc[r][2];
        }
        __syncthreads();

        // fused gates (item1 = tid, item2 = tid+256)
        {
            const int u = u1, r = r1;
            const float s0 = part[0][r][u]      + part[1][r][u]      + part[2][r][u]      + part[3][r][u];
            const float s1 = part[0][r][NU+u]   + part[1][r][NU+u]   + part[2][r][NU+u]   + part[3][r][NU+u];
            const float s2 = part[0][r][2*NU+u] + part[1][r][2*NU+u] + part[2][r][2*NU+u] + part[3][r][2*NU+u];
            const float rg = 1.f/(1.f + expf(-(xg10 + s0 + bh1r)));
            const float zg = 1.f/(1.f + expf(-(xg11 + s1 + bh1z)));
            const float ng = tanhf(xg12 + rg*(s2 + bh1n));
            const float hp = (t > 0) ? hsl[ug1*ROWS + r] : 0.f;
            hout[(size_t)ug1*B_ + b0 + r] = (1.f - zg)*ng + zg*hp;
        }
        if (has2) {
            const int u = u2, r = r2;
            const float s0 = part[0][r][u]      + part[1][r][u]      + part[2][r][u]      + part[3][r][u];
            const float s1 = part[0][r][NU+u]   + part[1][r][NU+u]   + part[2][r][NU+u]   + part[3][r][NU+u];
            const float s2 = part[0][r][2*NU+u] + part[1][r][2*NU+u] + part[2][r][2*NU+u] + part[3][r][2*NU+u];
            const float rg = 1.f/(1.f + expf(-(xg20 + s0 + bh2r)));
            const float zg = 1.f/(1.f + expf(-(xg21 + s1 + bh2z)));
            const float ng = tanhf(xg22 + rg*(s2 + bh2n));
            const float hp = (t > 0) ? hsl[ug2*ROWS + r] : 0.f;
            hout[(size_t)ug2*B_ + b0 + r] = (1.f - zg)*ng + zg*hp;
        }
        __syncthreads();   // drains vmcnt: h(t) stores complete before publish
        if (tid == 0) {
            __threadfence();
            __hip_atomic_fetch_add(mybar, 1, __ATOMIC_RELEASE, __HIP_MEMORY_SCOPE_AGENT);
        }
    }
}

// ---------------------------------------------------------------------------
// K3: heads on temporal [t][u][b]
// ---------------------------------------------------------------------------
__global__ __launch_bounds__(256) void k_heads2(const float* __restrict__ temporal,
                                                const float* __restrict__ Wcat,
                                                const float* __restrict__ bc,
                                                const float* __restrict__ bf,
                                                float* __restrict__ cs,
                                                float* __restrict__ fine_out) {
    const int t = blockIdx.x;       // 0..95
    const int b = threadIdx.x;      // 0..255
    const float* tb = temporal + (size_t)t*HB_ + b;
    float acc[31];
    #pragma unroll
    for (int c = 0; c < 31; ++c) acc[c] = 0.f;
    for (int u = 0; u < H_; ++u) {
        const float x = tb[(size_t)u*B_];
        const float* wrow = Wcat + u*32;
        #pragma unroll
        for (int c = 0; c < 31; ++c) acc[c] = fmaf(x, wrow[c], acc[c]);
    }
    const float l0 = acc[0] + bc[0], l1 = acc[1] + bc[1];
    const float m  = fmaxf(l0, l1);
    const float e0 = expf(l0 - m), e1 = expf(l1 - m);
    const float inv = 1.f/(e0 + e1);
    cs[((size_t)b*T_ + t)*2]     = e0*inv;
    cs[((size_t)b*T_ + t)*2 + 1] = e1*inv;
    #pragma unroll
    for (int c = 2; c < 31; ++c) {
        fine_out[((size_t)b*T_ + t)*NC_ + (c-2)] = 1.f/(1.f + expf(-(acc[c] + bf[c-2])));
    }
}

// ---------------------------------------------------------------------------
// K4: NMS + argmax
// ---------------------------------------------------------------------------
__global__ __launch_bounds__(256) void k_nms(const float* __restrict__ cs,
                                             float* __restrict__ out_dec,
                                             float* __restrict__ out_nms) {
    const int idx = blockIdx.x*256 + threadIdx.x;   // < 24576
    const int t = idx % T_;
    const float bg = cs[idx*2], s1 = cs[idx*2+1];
    float wmin = bg;
    #pragma unroll
    for (int dt = -2; dt <= 2; ++dt) {
        const int tt = t + dt;
        if (dt != 0 && tt >= 0 && tt < T_) wmin = fminf(wmin, cs[(idx + dt)*2]);
    }
    const bool keep = (bg <= wmin);
    out_dec[idx]     = (keep && (s1 > bg)) ? 1.f : 0.f;
    out_nms[idx*2]   = keep ? bg : 0.f;
    out_nms[idx*2+1] = keep ? s1 : 0.f;
}

// ---------------------------------------------------------------------------
extern "C" void kernel_launch(void* const* d_in, const int* in_sizes, int n_in,
                              void* d_out, int out_size, void* d_ws, size_t ws_size,
                              hipStream_t stream) {
    const float* features = (const float*)d_in[0];
    const float* Wi = (const float*)d_in[2];
    const float* Wh = (const float*)d_in[3];
    const float* bi = (const float*)d_in[4];
    const float* bh = (const float*)d_in[5];
    const float* Wc = (const float*)d_in[6];
    const float* bc = (const float*)d_in[7];
    const float* Wf = (const float*)d_in[8];
    const float* bf = (const float*)d_in[9];

    float* out = (float*)d_out;
    float* out_dec  = out;                 // (B,T)     24576
    float* out_nms  = out + BT_;           // (B,T,2)   49152
    float* out_fine = out + BT_ + 2*BT_;   // (B,T,29)  712704

    // workspace (floats): xproj | Wq | temporal | bar (2048 ints)
    // total 36,601,856 floats < round-0's proven 36,648,960 footprint.
    float* xproj    = (float*)d_ws;
    float4* Wq      = (float4*)(xproj + (size_t)BT_*G3_);
    float* temporal = xproj + (size_t)BT_*G3_ + (size_t)92*WQCOLS*4;
    int*   bar      = (int*)(temporal + (size_t)T_*HB_);
    float* Wcat     = xproj;               // xproj dead after GRU
    float* cs       = xproj + 12288;

    k_zero_bar<<<8, 256, 0, stream>>>(bar);
    k_prep_wq<<<414, 256, 0, stream>>>(Wh, Wq);
    k_xproj_gemm<<<dim3(9, 192), 256, 0, stream>>>(features, Wi, bi, xproj);
    k_gru_all<<<256, 256, 0, stream>>>(xproj, Wq, bh, temporal, bar);
    k_prep_wcat<<<46, 256, 0, stream>>>(Wc, Wf, Wcat);
    k_heads2<<<96, 256, 0, stream>>>(temporal, Wcat, bc, bf, cs, out_fine);
    k_nms<<<96, 256, 0, stream>>>(cs, out_dec, out_nms);
}

// Round 5
// 1333.369 us; speedup vs baseline: 2.0286x; 2.0286x over previous
//
#include <hip/hip_runtime.h>
#include <hip/hip_bf16.h>

// Problem constants
#define B_ 256
#define T_ 96
#define F_ 368
#define H_ 368
#define G3_ 1104          // 3*H
#define NC_ 29            // fine classes
#define BT_ (B_*T_)       // 24576
#define HB_ (H_*B_)       // 94208, one time-slice of temporal [u][b]

// GRU geometry
#define NSL 8             // unit slices
#define NU 46             // units per slice (8*46 = 368)
#define NCOL 138          // cols per slice = 3*NU
#define SLSTRIDE 144      // padded col positions per slice (64+64+16)
#define WQCOLS 1152       // 8 * 144
#define ROWS 8            // batch rows per group

#define F4C(v, i) ((i)==0?(v).x:((i)==1?(v).y:((i)==2?(v).z:(v).w)))

// ---- fence-free cross-XCD exchange primitives -----------------------------
// RELAXED agent-scope atomics compile to global_load/store with sc0+sc1:
// bypass L1/L2, complete at the cross-XCD coherence point, NO cache
// maintenance (the round-4 killer was acquire/fence buffer_inv nuking L2).
__device__ __forceinline__ void bstore_f(float* p, float v) {
    __hip_atomic_store(p, v, __ATOMIC_RELAXED, __HIP_MEMORY_SCOPE_AGENT);
}
__device__ __forceinline__ float2 bload_f2(const float* p) {
    unsigned long long v = __hip_atomic_load(
        reinterpret_cast<const unsigned long long*>(p),
        __ATOMIC_RELAXED, __HIP_MEMORY_SCOPE_AGENT);
    float2 f2; __builtin_memcpy(&f2, &v, 8);
    return f2;
}

// ---------------------------------------------------------------------------
// K0: pack Wh (1104x368) into Wq float4 blocks [kb=92][1152 colpos]
// ---------------------------------------------------------------------------
__global__ __launch_bounds__(256) void k_prep_wq(const float* __restrict__ Wh,
                                                 float4* __restrict__ Wq) {
    const int idx = blockIdx.x*256 + threadIdx.x;   // < 92*1152 = 105984
    const int kb = idx / WQCOLS, cp = idx - kb*WQCOLS;
    const int us = cp / SLSTRIDE, r = cp - us*SLSTRIDE;
    float4 v = make_float4(0.f,0.f,0.f,0.f);
    if (r < NCOL) {
        const int g = r / NU, u = r - g*NU;
        const int grow = g*H_ + us*NU + u;          // < 1104
        v = *reinterpret_cast<const float4*>(Wh + (size_t)grow*H_ + 4*kb);
    }
    Wq[idx] = v;
}

// ---------------------------------------------------------------------------
// K0b: pack head weights Wcat[u][32]
// ---------------------------------------------------------------------------
__global__ __launch_bounds__(256) void k_prep_wcat(const float* __restrict__ Wc,
                                                   const float* __restrict__ Wf,
                                                   float* __restrict__ Wcat) {
    const int idx = blockIdx.x*256 + threadIdx.x;   // < 368*32 = 11776
    const int u = idx >> 5, c = idx & 31;
    float v = 0.f;
    if (c < 2) v = Wc[c*H_ + u];
    else if (c < 31) v = Wf[(c-2)*H_ + u];
    Wcat[idx] = v;
}

// ---------------------------------------------------------------------------
// K0c: zero barrier counters AT THE COHERENCE POINT (bypass stores, so the
// gru spin's bypass loads can never see a stale cached zero/poison).
// ---------------------------------------------------------------------------
__global__ __launch_bounds__(256) void k_zero_bar(int* __restrict__ bar) {
    __hip_atomic_store(bar + blockIdx.x*256 + threadIdx.x, 0,
                       __ATOMIC_RELAXED, __HIP_MEMORY_SCOPE_AGENT);
}

// ---------------------------------------------------------------------------
// K1: xproj GEMM, 128x128 tile, software-pipelined global loads (unchanged).
// ---------------------------------------------------------------------------
__global__ __launch_bounds__(256) void k_xproj_gemm(const float* __restrict__ A,
                                                    const float* __restrict__ Bw,
                                                    const float* __restrict__ bias,
                                                    float* __restrict__ C) {
    __shared__ float As[16][128];
    __shared__ float Bs[16][128];
    const int tid = threadIdx.x;
    const int tx = tid & 15, ty = tid >> 4;
    const int gm0 = blockIdx.y * 128, gn0 = blockIdx.x * 128;
    const float4* A4 = reinterpret_cast<const float4*>(A);   // row stride 92
    const float4* B4 = reinterpret_cast<const float4*>(Bw);
    const int lm = tid & 127;
    const int kh = (tid >> 7) * 2;
    const int gn = gn0 + lm;

    float acc[8][8];
    #pragma unroll
    for (int i = 0; i < 8; ++i)
        #pragma unroll
        for (int j = 0; j < 8; ++j) acc[i][j] = 0.f;

    float4 va[2], vb[2];
    #pragma unroll
    for (int q = 0; q < 2; ++q) {
        va[q] = A4[(size_t)(gm0 + lm)*92 + kh + q];
        vb[q] = (gn < G3_) ? B4[(size_t)gn*92 + kh + q] : make_float4(0.f,0.f,0.f,0.f);
    }

    for (int kt = 0; kt < 23; ++kt) {
        __syncthreads();
        #pragma unroll
        for (int q = 0; q < 2; ++q) {
            As[(kh+q)*4+0][lm] = va[q].x; As[(kh+q)*4+1][lm] = va[q].y;
            As[(kh+q)*4+2][lm] = va[q].z; As[(kh+q)*4+3][lm] = va[q].w;
            Bs[(kh+q)*4+0][lm] = vb[q].x; Bs[(kh+q)*4+1][lm] = vb[q].y;
            Bs[(kh+q)*4+2][lm] = vb[q].z; Bs[(kh+q)*4+3][lm] = vb[q].w;
        }
        __syncthreads();
        const int ktn = (kt < 22) ? kt + 1 : 22;
        #pragma unroll
        for (int q = 0; q < 2; ++q) {
            va[q] = A4[(size_t)(gm0 + lm)*92 + ktn*4 + kh + q];
            vb[q] = (gn < G3_) ? B4[(size_t)gn*92 + ktn*4 + kh + q]
                               : make_float4(0.f,0.f,0.f,0.f);
        }
        #pragma unroll
        for (int k = 0; k < 16; ++k) {
            const float4 a0 = *reinterpret_cast<const float4*>(&As[k][ty*4]);
            const float4 a1 = *reinterpret_cast<const float4*>(&As[k][64 + ty*4]);
            const float4 b0 = *reinterpret_cast<const float4*>(&Bs[k][tx*4]);
            const float4 b1 = *reinterpret_cast<const float4*>(&Bs[k][64 + tx*4]);
            #pragma unroll
            for (int i = 0; i < 4; ++i) {
                const float ai0 = F4C(a0, i), ai1 = F4C(a1, i);
                #pragma unroll
                for (int j = 0; j < 4; ++j) {
                    const float bj0 = F4C(b0, j), bj1 = F4C(b1, j);
                    acc[i][j]     = fmaf(ai0, bj0, acc[i][j]);
                    acc[i][j+4]   = fmaf(ai0, bj1, acc[i][j+4]);
                    acc[i+4][j]   = fmaf(ai1, bj0, acc[i+4][j]);
                    acc[i+4][j+4] = fmaf(ai1, bj1, acc[i+4][j+4]);
                }
            }
        }
    }
    #pragma unroll
    for (int i = 0; i < 8; ++i) {
        const int gm = gm0 + ((i < 4) ? (ty*4 + i) : (64 + ty*4 + i - 4));
        #pragma unroll
        for (int j = 0; j < 8; ++j) {
            const int gnn = gn0 + ((j < 4) ? (tx*4 + j) : (64 + tx*4 + j - 4));
            if (gnn < G3_) C[(size_t)gm*G3_ + gnn] = acc[i][j] + bias[gnn];
        }
    }
}

// ---------------------------------------------------------------------------
// K2 v4: PERSISTENT GRU, fence-free. 256 WGs = 32 bg x 8 us. us=blockIdx&7
// so the 32 WGs sharing a Wq slice share one XCD's L2 (212 KB, ~100% hit).
// All cross-WG traffic (h exchange + barrier flags) uses RELAXED agent
// atomics (L1/L2-bypass) -> NO cache invalidation, W stays L2-resident.
// Store->flag ordering comes from the vmcnt(0) each wave's __syncthreads
// performs before s_barrier. Correct under any WG->XCD mapping.
// ---------------------------------------------------------------------------
__global__ __launch_bounds__(256) void k_gru_all(const float* __restrict__ xproj,
                                                 const float4* __restrict__ Wq,
                                                 const float* __restrict__ bh,
                                                 float* __restrict__ temporal,
                                                 int* __restrict__ bar) {
    __shared__ float part[4][ROWS][SLSTRIDE];   // 18,432 B
    __shared__ float hsl[H_*ROWS];              // staged h(t-1)[u][r], 11,776 B
    const int tid = threadIdx.x;
    const int us  = blockIdx.x & 7;             // Wq slice (XCD-local under %8)
    const int bg  = blockIdx.x >> 3;            // 0..31
    const int b0  = bg * ROWS;
    const int wq  = tid >> 6;                   // k-quarter (wave id)
    const int l   = tid & 63;
    const int l3  = 128 + (l & 15);
    int* mybar = bar + bg*64;                   // 256 B spacing

    // constant gate-phase indices
    const int u1 = tid % NU, r1 = tid / NU;     // item1 = tid (always valid)
    const int ug1 = us*NU + u1;
    const int i2 = tid + 256;
    const int u2 = i2 % NU, r2 = i2 / NU;       // item2 valid iff tid < 112
    const int ug2 = us*NU + u2;
    const bool has2 = (i2 < ROWS*NU);

    const float bh1r = bh[ug1], bh1z = bh[H_+ug1], bh1n = bh[2*H_+ug1];
    float bh2r = 0.f, bh2z = 0.f, bh2n = 0.f;
    if (has2) { bh2r = bh[ug2]; bh2z = bh[H_+ug2]; bh2n = bh[2*H_+ug2]; }

    const float4* wp  = Wq + (size_t)(wq*23)*WQCOLS + us*SLSTRIDE;
    const float4* hs4 = reinterpret_cast<const float4*>(hsl) + (size_t)wq*184;

    for (int t = 0; t < T_; ++t) {
        float* hout = temporal + (size_t)t*HB_;

        // prefetch gate operands (plain cached loads; xproj is pre-kernel data)
        const float* xr1 = xproj + ((size_t)(b0 + r1)*T_ + t)*G3_;
        const float xg10 = xr1[ug1], xg11 = xr1[H_+ug1], xg12 = xr1[2*H_+ug1];
        float xg20 = 0.f, xg21 = 0.f, xg22 = 0.f;
        if (has2) {
            const float* xr2 = xproj + ((size_t)(b0 + r2)*T_ + t)*G3_;
            xg20 = xr2[ug2]; xg21 = xr2[H_+ug2]; xg22 = xr2[2*H_+ug2];
        }

        float acc[ROWS][3];
        #pragma unroll
        for (int r = 0; r < ROWS; ++r) { acc[r][0]=0.f; acc[r][1]=0.f; acc[r][2]=0.f; }

        if (t > 0) {
            // wait for all 8 bg-siblings to publish h(t-1). RELAXED poll:
            // no cache maintenance; reads the coherence point directly.
            if (tid == 0) {
                while (__hip_atomic_load(mybar, __ATOMIC_RELAXED,
                                         __HIP_MEMORY_SCOPE_AGENT) < 8*t) {}
            }
            __syncthreads();
            const float* hin = temporal + (size_t)(t - 1)*HB_;
            // stage h(t-1)[all u][8 rows] via bypass 8B loads: 1472 slots
            #pragma unroll
            for (int ii = 0; ii < 6; ++ii) {
                const int s = tid + ii*256;
                if (s < H_*ROWS/2) {
                    const int u = s >> 2, pr = s & 3;
                    const float2 v = bload_f2(hin + (size_t)u*B_ + b0 + 2*pr);
                    hsl[u*8 + 2*pr]     = v.x;
                    hsl[u*8 + 2*pr + 1] = v.y;
                }
            }
            __syncthreads();
            // inner product: 23 kk, W software-pipelined from (resident) L2
            float4 w0 = wp[l], w1 = wp[64 + l], w2 = wp[l3];
            for (int kk = 0; kk < 23; ++kk) {
                const int kkn = (kk < 22) ? kk + 1 : 22;
                const float4* np = wp + (size_t)kkn*WQCOLS;
                const float4 nw0 = np[l], nw1 = np[64 + l], nw2 = np[l3];
                #pragma unroll
                for (int jk = 0; jk < 4; ++jk) {
                    const float4 h0 = hs4[kk*8 + jk*2];
                    const float4 h1 = hs4[kk*8 + jk*2 + 1];
                    const float wa = F4C(w0, jk), wb = F4C(w1, jk), wc = F4C(w2, jk);
                    #pragma unroll
                    for (int r = 0; r < 4; ++r) {
                        const float hv = F4C(h0, r);
                        acc[r][0] = fmaf(hv, wa, acc[r][0]);
                        acc[r][1] = fmaf(hv, wb, acc[r][1]);
                        acc[r][2] = fmaf(hv, wc, acc[r][2]);
                    }
                    #pragma unroll
                    for (int r = 0; r < 4; ++r) {
                        const float hv = F4C(h1, r);
                        acc[4+r][0] = fmaf(hv, wa, acc[4+r][0]);
                        acc[4+r][1] = fmaf(hv, wb, acc[4+r][1]);
                        acc[4+r][2] = fmaf(hv, wc, acc[4+r][2]);
                    }
                }
                w0 = nw0; w1 = nw1; w2 = nw2;
            }
        }

        // k-quarter partials
        #pragma unroll
        for (int r = 0; r < ROWS; ++r) {
            part[wq][r][l]      = acc[r][0];
            part[wq][r][64 + l] = acc[r][1];
            part[wq][r][l3]     = acc[r][2];
        }
        __syncthreads();

        // fused gates; h(t) published via bypass stores
        {
            const int u = u1, r = r1;
            const float s0 = part[0][r][u]      + part[1][r][u]      + part[2][r][u]      + part[3][r][u];
            const float s1 = part[0][r][NU+u]   + part[1][r][NU+u]   + part[2][r][NU+u]   + part[3][r][NU+u];
            const float s2 = part[0][r][2*NU+u] + part[1][r][2*NU+u] + part[2][r][2*NU+u] + part[3][r][2*NU+u];
            const float rg = 1.f/(1.f + expf(-(xg10 + s0 + bh1r)));
            const float zg = 1.f/(1.f + expf(-(xg11 + s1 + bh1z)));
            const float ng = tanhf(xg12 + rg*(s2 + bh1n));
            const float hp = (t > 0) ? hsl[ug1*ROWS + r] : 0.f;
            bstore_f(hout + (size_t)ug1*B_ + b0 + r, (1.f - zg)*ng + zg*hp);
        }
        if (has2) {
            const int u = u2, r = r2;
            const float s0 = part[0][r][u]      + part[1][r][u]      + part[2][r][u]      + part[3][r][u];
            const float s1 = part[0][r][NU+u]   + part[1][r][NU+u]   + part[2][r][NU+u]   + part[3][r][NU+u];
            const float s2 = part[0][r][2*NU+u] + part[1][r][2*NU+u] + part[2][r][2*NU+u] + part[3][r][2*NU+u];
            const float rg = 1.f/(1.f + expf(-(xg20 + s0 + bh2r)));
            const float zg = 1.f/(1.f + expf(-(xg21 + s1 + bh2z)));
            const float ng = tanhf(xg22 + rg*(s2 + bh2n));
            const float hp = (t > 0) ? hsl[ug2*ROWS + r] : 0.f;
            bstore_f(hout + (size_t)ug2*B_ + b0 + r, (1.f - zg)*ng + zg*hp);
        }
        // each wave's __syncthreads drains its vmcnt before s_barrier =>
        // all bypass stores are complete at the coherence point here.
        __syncthreads();
        if (tid == 0) {
            __hip_atomic_fetch_add(mybar, 1, __ATOMIC_RELAXED,
                                   __HIP_MEMORY_SCOPE_AGENT);
        }
    }
}

// ---------------------------------------------------------------------------
// K3: heads on temporal [t][u][b] (kernel boundary = full visibility)
// ---------------------------------------------------------------------------
__global__ __launch_bounds__(256) void k_heads2(const float* __restrict__ temporal,
                                                const float* __restrict__ Wcat,
                                                const float* __restrict__ bc,
                                                const float* __restrict__ bf,
                                                float* __restrict__ cs,
                                                float* __restrict__ fine_out) {
    const int t = blockIdx.x;       // 0..95
    const int b = threadIdx.x;      // 0..255
    const float* tb = temporal + (size_t)t*HB_ + b;
    float acc[31];
    #pragma unroll
    for (int c = 0; c < 31; ++c) acc[c] = 0.f;
    for (int u = 0; u < H_; ++u) {
        const float x = tb[(size_t)u*B_];
        const float* wrow = Wcat + u*32;
        #pragma unroll
        for (int c = 0; c < 31; ++c) acc[c] = fmaf(x, wrow[c], acc[c]);
    }
    const float l0 = acc[0] + bc[0], l1 = acc[1] + bc[1];
    const float m  = fmaxf(l0, l1);
    const float e0 = expf(l0 - m), e1 = expf(l1 - m);
    const float inv = 1.f/(e0 + e1);
    cs[((size_t)b*T_ + t)*2]     = e0*inv;
    cs[((size_t)b*T_ + t)*2 + 1] = e1*inv;
    #pragma unroll
    for (int c = 2; c < 31; ++c) {
        fine_out[((size_t)b*T_ + t)*NC_ + (c-2)] = 1.f/(1.f + expf(-(acc[c] + bf[c-2])));
    }
}

// ---------------------------------------------------------------------------
// K4: NMS + argmax
// ---------------------------------------------------------------------------
__global__ __launch_bounds__(256) void k_nms(const float* __restrict__ cs,
                                             float* __restrict__ out_dec,
                                             float* __restrict__ out_nms) {
    const int idx = blockIdx.x*256 + threadIdx.x;   // < 24576
    const int t = idx % T_;
    const float bg = cs[idx*2], s1 = cs[idx*2+1];
    float wmin = bg;
    #pragma unroll
    for (int dt = -2; dt <= 2; ++dt) {
        const int tt = t + dt;
        if (dt != 0 && tt >= 0 && tt < T_) wmin = fminf(wmin, cs[(idx + dt)*2]);
    }
    const bool keep = (bg <= wmin);
    out_dec[idx]     = (keep && (s1 > bg)) ? 1.f : 0.f;
    out_nms[idx*2]   = keep ? bg : 0.f;
    out_nms[idx*2+1] = keep ? s1 : 0.f;
}

// ---------------------------------------------------------------------------
extern "C" void kernel_launch(void* const* d_in, const int* in_sizes, int n_in,
                              void* d_out, int out_size, void* d_ws, size_t ws_size,
                              hipStream_t stream) {
    const float* features = (const float*)d_in[0];
    const float* Wi = (const float*)d_in[2];
    const float* Wh = (const float*)d_in[3];
    const float* bi = (const float*)d_in[4];
    const float* bh = (const float*)d_in[5];
    const float* Wc = (const float*)d_in[6];
    const float* bc = (const float*)d_in[7];
    const float* Wf = (const float*)d_in[8];
    const float* bf = (const float*)d_in[9];

    float* out = (float*)d_out;
    float* out_dec  = out;                 // (B,T)     24576
    float* out_nms  = out + BT_;           // (B,T,2)   49152
    float* out_fine = out + BT_ + 2*BT_;   // (B,T,29)  712704

    // workspace (floats): xproj | Wq | temporal | bar (2048 ints)
    float* xproj    = (float*)d_ws;
    float4* Wq      = (float4*)(xproj + (size_t)BT_*G3_);
    float* temporal = xproj + (size_t)BT_*G3_ + (size_t)92*WQCOLS*4;
    int*   bar      = (int*)(temporal + (size_t)T_*HB_);
    float* Wcat     = xproj;               // xproj dead after GRU
    float* cs       = xproj + 12288;

    k_zero_bar<<<8, 256, 0, stream>>>(bar);
    k_prep_wq<<<414, 256, 0, stream>>>(Wh, Wq);
    k_xproj_gemm<<<dim3(9, 192), 256, 0, stream>>>(features, Wi, bi, xproj);
    k_gru_all<<<256, 256, 0, stream>>>(xproj, Wq, bh, temporal, bar);
    k_prep_wcat<<<46, 256, 0, stream>>>(Wc, Wf, Wcat);
    k_heads2<<<96, 256, 0, stream>>>(temporal, Wcat, bc, bf, cs, out_fine);
    k_nms<<<96, 256, 0, stream>>>(cs, out_dec, out_nms);
}